// Round 9
// baseline (115.416 us; speedup 1.0000x reference)
//
#include <hip/hip_runtime.h>

// VectorQuantizer forward via fp16 MFMA (single-term), register codebook:
//   x          [64,32,32,64] f32  -> flat [N=65536, D=64]
//   embeddings [D=64, K=512] f32  (codes are COLUMNS)
//   out = x + (q - x),  q = argmin_k ||f - e_k||^2 ;  loss = 1.25*mean((q-x)^2)
//
// argmin_k ||f-e_k||^2 == argmin_k (en2[k] - 2 f.e_k)  (row term r2 common).
// Approx dot = fp16(f).fp16(e) via mfma_f32_16x16x32_f16. Metric error sigma
// ~2.7e-4 (fp16 mantissa 10b) — SMALLER than the validated bf16-2-term of
// rounds 7/8 (sigma ~3.4e-4), so TAU=6e-3 keeps the proven >=17-sigma margin.
// Rows whose approx top-2 gap < TAU get an exact f32 rescan with round-2-
// identical arithmetic (f staged via LDS broadcast -> ~30 VGPRs, no pressure
// cliff). en2b = en2 + 6 keeps the metric positive -> u32 bit-monotone pack,
// code index in low 9 bits == np.argmin first-index tie-break.
//
// Occupancy: wave owns 64 codes (32 VGPR of A-frags, round-5-proven resident),
// LDS ~11 KB, 512 blocks x 8 waves all resident, 4+ waves/SIMD.

#define N_ROWS 65536
#define DIM 64
#define KCODES 512
#define ROWS_PER_BLOCK 128   // 8 bt tiles of 16 rows
#define THREADS 512

typedef _Float16 f16x8 __attribute__((ext_vector_type(8)));
typedef float f32x4 __attribute__((ext_vector_type(4)));

// ws byte offsets
#define LOSS_OFF   0
#define EN2_OFF    256
#define EN2B_OFF   2304
#define ET_OFF     4352
#define AFR_OFF    135424   // fp16 frag codebook: 512*64*2B = 64 KB

#define TAU 6.0e-3f

// ---------------- prep: codebook only (2 blocks x 256 threads)
__global__ void vq_prep(const float* __restrict__ emb, char* __restrict__ ws) {
    const int k = blockIdx.x * 256 + threadIdx.x;   // code 0..511
    if (k == 0) *(double*)(ws + LOSS_OFF) = 0.0;
    float* en2  = (float*)(ws + EN2_OFF);
    float* en2b = (float*)(ws + EN2B_OFF);
    float* eT   = (float*)(ws + ET_OFF);
    f16x8* Afr  = (f16x8*)(ws + AFR_OFF);
    const int ctg = k >> 4, c = k & 15;
    float s = 0.0f;
    #pragma unroll
    for (int ks = 0; ks < 2; ++ks) {
        #pragma unroll
        for (int g = 0; g < 4; ++g) {
            f16x8 H;
            #pragma unroll
            for (int j = 0; j < 8; ++j) {
                const int d = ks * 32 + g * 8 + j;
                const float v = emb[d * KCODES + k];   // coalesced across k
                eT[k * DIM + d] = v;
                s = fmaf(v, v, s);                     // same chain as round-2
                H[j] = (_Float16)v;                    // RTNE
            }
            Afr[(ctg * 2 + ks) * 64 + (g * 16 + c)] = H;
        }
    }
    en2[k] = s;
    en2b[k] = s + 6.0f;
}

// ---------------- main
__global__ __launch_bounds__(THREADS, 4)
void vq_main(const float* __restrict__ x, const char* __restrict__ ws,
             float* __restrict__ out, double* __restrict__ loss_acc) {
    __shared__ unsigned long long sm_all[8][8][16];   // 8 KB
    __shared__ float fbuf[8][DIM];                    // 2 KB: fallback row stage
    __shared__ unsigned pick[ROWS_PER_BLOCK];
    __shared__ unsigned short llist[ROWS_PER_BLOCK];
    __shared__ double lpart[8];
    __shared__ int lcnt;

    const int tid = threadIdx.x;
    const int bid = blockIdx.x;
    const int w = __builtin_amdgcn_readfirstlane(tid >> 6);  // wave 0..7 = 64-code group
    const int l = tid & 63;
    if (tid == 0) lcnt = 0;

    // A-fragments: this wave's 64 codes (4 ctiles x 2 ksteps) = 32 VGPRs.
    const f16x8* Afr = (const f16x8*)(ws + AFR_OFF);
    f16x8 Ah[4][2];
    #pragma unroll
    for (int ct = 0; ct < 4; ++ct) {
        #pragma unroll
        for (int ks = 0; ks < 2; ++ks)
            Ah[ct][ks] = Afr[((w * 4 + ct) * 2 + ks) * 64 + l];
    }
    const float* en2b = (const float*)(ws + EN2B_OFF);
    f32x4 enf[4];
    #pragma unroll
    for (int ct = 0; ct < 4; ++ct) {
        const float4 t = *(const float4*)(en2b + w * 64 + ct * 16 + (l >> 4) * 4);
        enf[ct][0] = t.x; enf[ct][1] = t.y; enf[ct][2] = t.z; enf[ct][3] = t.w;
    }
    const int codebase = w * 64 + (l >> 4) * 4;

    // Scan: 8 row-tiles of 16; every wave scans its 64 codes against all rows.
    #pragma unroll 2
    for (int bt = 0; bt < 8; ++bt) {
        const int rowb = bid * ROWS_PER_BLOCK + bt * 16 + (l & 15);
        const float* px = x + (size_t)rowb * DIM + (l >> 4) * 8;
        const float4 v0 = *(const float4*)px;
        const float4 v1 = *(const float4*)(px + 4);
        const float4 v2 = *(const float4*)(px + 32);
        const float4 v3 = *(const float4*)(px + 36);
        f16x8 bh0, bh1;
        bh0[0] = (_Float16)v0.x; bh0[1] = (_Float16)v0.y;
        bh0[2] = (_Float16)v0.z; bh0[3] = (_Float16)v0.w;
        bh0[4] = (_Float16)v1.x; bh0[5] = (_Float16)v1.y;
        bh0[6] = (_Float16)v1.z; bh0[7] = (_Float16)v1.w;
        bh1[0] = (_Float16)v2.x; bh1[1] = (_Float16)v2.y;
        bh1[2] = (_Float16)v2.z; bh1[3] = (_Float16)v2.w;
        bh1[4] = (_Float16)v3.x; bh1[5] = (_Float16)v3.y;
        bh1[6] = (_Float16)v3.z; bh1[7] = (_Float16)v3.w;

        unsigned m1 = 0xFFFFFFFFu, m2 = 0xFFFFFFFFu;
        #pragma unroll
        for (int ct = 0; ct < 4; ++ct) {
            f32x4 a = {0.f, 0.f, 0.f, 0.f};
            a = __builtin_amdgcn_mfma_f32_16x16x32_f16(Ah[ct][0], bh0, a, 0, 0, 0);
            a = __builtin_amdgcn_mfma_f32_16x16x32_f16(Ah[ct][1], bh1, a, 0, 0, 0);
            #pragma unroll
            for (int rg = 0; rg < 4; ++rg) {
                const float m = fmaf(-2.0f, a[rg], enf[ct][rg]);
                const unsigned u = (__float_as_uint(m) & 0xFFFFFE00u)
                                 | (unsigned)(codebase + ct * 16 + rg);
                const unsigned hi = m1 > u ? m1 : u;
                m1 = m1 < u ? m1 : u;
                m2 = m2 < hi ? m2 : hi;
            }
        }
        #pragma unroll
        for (int mask = 16; mask <= 32; mask <<= 1) {
            const unsigned o1 = __shfl_xor(m1, mask);
            const unsigned o2 = __shfl_xor(m2, mask);
            const unsigned hi  = m1 > o1 ? m1 : o1;
            const unsigned lo2 = m2 < o2 ? m2 : o2;
            m1 = m1 < o1 ? m1 : o1;
            m2 = hi < lo2 ? hi : lo2;
        }
        if (l < 16) sm_all[bt][w][l] = ((unsigned long long)m1 << 32) | m2;
    }
    __syncthreads();

    // combine the 8 waves' results per row; flag near-ties for exact rescan
    if (tid < ROWS_PER_BLOCK) {
        const int bt = tid >> 4, c = tid & 15;
        unsigned long long p = sm_all[bt][0][c];
        unsigned m1 = (unsigned)(p >> 32), m2 = (unsigned)p;
        #pragma unroll
        for (int w2 = 1; w2 < 8; ++w2) {
            p = sm_all[bt][w2][c];
            const unsigned a1 = (unsigned)(p >> 32), a2 = (unsigned)p;
            const unsigned hi  = m1 > a1 ? m1 : a1;
            const unsigned lo2 = m2 < a2 ? m2 : a2;
            m1 = m1 < a1 ? m1 : a1;
            m2 = hi < lo2 ? hi : lo2;
        }
        pick[tid] = m1 & 0x1FFu;
        const float f1 = __uint_as_float(m1 & 0xFFFFFE00u);
        const float f2 = __uint_as_float(m2 & 0xFFFFFE00u);
        if (f2 - f1 < TAU) {
            const int idx = atomicAdd(&lcnt, 1);
            llist[idx] = (unsigned short)tid;
        }
    }
    __syncthreads();

    // Exact f32 fallback, round-2-identical arithmetic. One wave per flagged
    // row; the row is staged in LDS and read back via broadcast ds_reads so
    // no f[16] register array exists (fallback ~30 VGPRs live).
    {
        const float* eT  = (const float*)(ws + ET_OFF);
        const float* en2 = (const float*)(ws + EN2_OFF);
        const int nfb = lcnt;
        for (int i = w; i < nfb; i += 8) {
            const int r = llist[i];
            const int grow = bid * ROWS_PER_BLOCK + r;
            fbuf[w][l] = x[(size_t)grow * DIM + l];   // stage row (coalesced)
            const float4* fr = (const float4*)fbuf[w];
            float4 a4 = make_float4(0.f, 0.f, 0.f, 0.f);
            #pragma unroll
            for (int j = 0; j < 16; ++j) {
                const float4 f = fr[j];               // broadcast ds_read
                a4.x = fmaf(f.x, f.x, a4.x);
                a4.y = fmaf(f.y, f.y, a4.y);
                a4.z = fmaf(f.z, f.z, a4.z);
                a4.w = fmaf(f.w, f.w, a4.w);
            }
            const float r2 = (a4.x + a4.y) + (a4.z + a4.w);
            unsigned long long best = 0xFFFFFFFFFFFFFFFFull;
            for (int c8 = 0; c8 < 8; ++c8) {
                const int k = l * 8 + c8;
                const float4* ek = (const float4*)(eT + k * DIM);
                float4 acc4 = make_float4(0.f, 0.f, 0.f, 0.f);
                #pragma unroll
                for (int j = 0; j < 16; ++j) {
                    const float4 e = ek[j];
                    const float4 f = fr[j];
                    acc4.x = fmaf(f.x, e.x, acc4.x);
                    acc4.y = fmaf(f.y, e.y, acc4.y);
                    acc4.z = fmaf(f.z, e.z, acc4.z);
                    acc4.w = fmaf(f.w, e.w, acc4.w);
                }
                const float dot = (acc4.x + acc4.y) + (acc4.z + acc4.w);
                const float s = (r2 + en2[k]) - 2.0f * dot;
                const unsigned long long pk =
                    ((unsigned long long)__float_as_uint(s) << 32) | (unsigned)k;
                if (pk < best) best = pk;   // ascending k + strict < == np.argmin
            }
            #pragma unroll
            for (int mask = 1; mask <= 32; mask <<= 1) {
                const unsigned long long o = __shfl_xor(best, mask);
                if (o < best) best = o;
            }
            if (l == 0) pick[r] = (unsigned)best & 0x1FFu;
        }
    }
    __syncthreads();

    // out = x + (q - x) and loss: 4 threads per row, 16 floats each
    {
        const float* eT = (const float*)(ws + ET_OFF);
        const int r = tid >> 2, c4 = tid & 3;
        const int grow = bid * ROWS_PER_BLOCK + r;
        const float4* xr = (const float4*)(x + (size_t)grow * DIM) + c4 * 4;
        const float4* qr = (const float4*)(eT + pick[r] * DIM) + c4 * 4;
        float4* orow = ((float4*)out) + (size_t)grow * 16 + c4 * 4;
        float lsum = 0.0f;
        #pragma unroll
        for (int j = 0; j < 4; ++j) {
            const float4 q = qr[j], xv = xr[j];
            float4 o; float dx;
            dx = q.x - xv.x; o.x = xv.x + dx; lsum = fmaf(dx, dx, lsum);
            dx = q.y - xv.y; o.y = xv.y + dx; lsum = fmaf(dx, dx, lsum);
            dx = q.z - xv.z; o.z = xv.z + dx; lsum = fmaf(dx, dx, lsum);
            dx = q.w - xv.w; o.w = xv.w + dx; lsum = fmaf(dx, dx, lsum);
            orow[j] = o;
        }
        double dl = (double)lsum;
        #pragma unroll
        for (int off = 32; off > 0; off >>= 1) dl += __shfl_down(dl, off);
        if (l == 0) lpart[w] = dl;
    }
    __syncthreads();
    if (tid == 0) {
        double s = lpart[0];
        #pragma unroll
        for (int t = 1; t < 8; ++t) s += lpart[t];
        atomicAdd(loss_acc, s);
    }
}

__global__ void vq_fin(const double* __restrict__ loss_acc, float* __restrict__ out) {
    if (threadIdx.x == 0)
        out[N_ROWS * DIM] = (float)(1.25 * loss_acc[0] * (1.0 / (double)(N_ROWS * DIM)));
}

extern "C" void kernel_launch(void* const* d_in, const int* in_sizes, int n_in,
                              void* d_out, int out_size, void* d_ws, size_t ws_size,
                              hipStream_t stream) {
    const float* x   = (const float*)d_in[0];
    const float* emb = (const float*)d_in[1];
    float* out = (float*)d_out;
    char*  ws  = (char*)d_ws;

    vq_prep<<<2, 256, 0, stream>>>(emb, ws);
    vq_main<<<N_ROWS / ROWS_PER_BLOCK, THREADS, 0, stream>>>(
        x, ws, out, (double*)(ws + LOSS_OFF));
    vq_fin<<<1, 1, 0, stream>>>((const double*)(ws + LOSS_OFF), out);
}

// Round 10
// 114.270 us; speedup vs baseline: 1.0100x; 1.0100x over previous
//
#include <hip/hip_runtime.h>

// VectorQuantizer forward, phase-decoupled:
//   prep:   codebook -> ws (eT f32, en2, en2b, bf16-hi A-frags);
//           x -> bf16 hi/lo B-frags staged in d_out (round-5-validated layout)
//   scan:   MFMA distance scan -> pick|flag u16 per row (no epilogue)
//   finish: exact f32 rescan of flagged rows + coalesced out/loss
//   fin:    loss scalar
//
// Metric: argmin_k ||f-e_k||^2 == argmin_k (en2[k]-2 f.e_k). Approx dot =
// (fh+fl).eh (bf16), error sigma ~3e-4; TAU=6e-3 (validated rounds 7/8,
// absmax 0). Near-ties rescanned exactly with round-2-identical arithmetic.
// en2b = en2+6 keeps metric positive -> u32 bit-monotone pack, code idx in
// low 9 bits == np.argmin first-index tie-break.

#define N_ROWS 65536
#define DIM 64
#define KCODES 512

typedef short s16x8 __attribute__((ext_vector_type(8)));
typedef float f32x4 __attribute__((ext_vector_type(4)));

// ws byte offsets (total ~332 KB)
#define LOSS_OFF   0
#define EN2_OFF    256
#define EN2B_OFF   2304
#define ET_OFF     4352      // f32 codebook rows: 128 KB
#define AFR_OFF    135424    // bf16-hi A-frags: 64 KB
#define PICK_OFF   200960    // u16 pick|flag per row: 128 KB

#define TAU 6.0e-3f

__device__ __forceinline__ unsigned short f2bf(float f) {
    unsigned u = __float_as_uint(f);
    return (unsigned short)((u + 0x7fffu + ((u >> 16) & 1u)) >> 16);
}
__device__ __forceinline__ float bf2f(unsigned short h) {
    return __uint_as_float(((unsigned)h) << 16);
}

// ---------------- prep: blocks 0-1 codebook; blocks 2..1025 stage x-frags
__global__ void vq_prep(const float* __restrict__ x, const float* __restrict__ emb,
                        float* __restrict__ outbuf, char* __restrict__ ws) {
    const int bid = blockIdx.x, tid = threadIdx.x;
    if (bid < 2) {
        const int k = bid * 256 + tid;             // code 0..511
        if (k == 0) *(double*)(ws + LOSS_OFF) = 0.0;
        float* en2  = (float*)(ws + EN2_OFF);
        float* en2b = (float*)(ws + EN2B_OFF);
        float* eT   = (float*)(ws + ET_OFF);
        uint4* Afr  = (uint4*)(ws + AFR_OFF);
        const int ctg = k >> 4, c = k & 15;
        float s = 0.0f;
        #pragma unroll
        for (int ks = 0; ks < 2; ++ks) {
            #pragma unroll
            for (int g = 0; g < 4; ++g) {
                unsigned short hb[8];
                #pragma unroll
                for (int j = 0; j < 8; ++j) {
                    const int d = ks * 32 + g * 8 + j;
                    const float v = emb[d * KCODES + k];   // coalesced across k
                    eT[k * DIM + d] = v;
                    s = fmaf(v, v, s);                     // same chain as round-2
                    hb[j] = f2bf(v);
                }
                uint4 H;
                H.x = hb[0] | ((unsigned)hb[1] << 16); H.y = hb[2] | ((unsigned)hb[3] << 16);
                H.z = hb[4] | ((unsigned)hb[5] << 16); H.w = hb[6] | ((unsigned)hb[7] << 16);
                Afr[(ctg * 2 + ks) * 64 + (g * 16 + c)] = H;
            }
        }
        en2[k] = s;
        en2b[k] = s + 6.0f;
    } else {
        // x -> fragment-ordered bf16 hi/lo in d_out (round-5-validated layout)
        const int rt   = (bid - 2) * 4 + (tid >> 6);   // row-tile 0..4095
        const int lane = tid & 63;
        const int row  = rt * 16 + (lane & 15);
        const int g    = lane >> 4;
        uint4* X = (uint4*)outbuf;
        #pragma unroll
        for (int ks = 0; ks < 2; ++ks) {
            const float* p = x + (size_t)row * DIM + ks * 32 + g * 8;
            const float4 v0 = *(const float4*)p;
            const float4 v1 = *(const float4*)(p + 4);
            float vv[8] = {v0.x, v0.y, v0.z, v0.w, v1.x, v1.y, v1.z, v1.w};
            unsigned short hb[8], lb[8];
            #pragma unroll
            for (int j = 0; j < 8; ++j) {
                const unsigned short h = f2bf(vv[j]);
                hb[j] = h;
                lb[j] = f2bf(vv[j] - bf2f(h));
            }
            uint4 H, L;
            H.x = hb[0] | ((unsigned)hb[1] << 16); H.y = hb[2] | ((unsigned)hb[3] << 16);
            H.z = hb[4] | ((unsigned)hb[5] << 16); H.w = hb[6] | ((unsigned)hb[7] << 16);
            L.x = lb[0] | ((unsigned)lb[1] << 16); L.y = lb[2] | ((unsigned)lb[3] << 16);
            L.z = lb[4] | ((unsigned)lb[5] << 16); L.w = lb[6] | ((unsigned)lb[7] << 16);
            X[((rt * 2 + ks) * 2 + 0) * 64 + lane] = H;
            X[((rt * 2 + ks) * 2 + 1) * 64 + lane] = L;
        }
    }
}

// ---------------- scan: picks + near-tie flags only
__global__ __launch_bounds__(512, 2)
void vq_scan(const float* __restrict__ xfrag, const char* __restrict__ ws,
             unsigned short* __restrict__ pickf) {
    __shared__ unsigned long long sm_all[8][8][16];   // 8 KB

    const int tid = threadIdx.x;
    const int bid = blockIdx.x;
    const int w = __builtin_amdgcn_readfirstlane(tid >> 6);  // wave = 64-code group
    const int l = tid & 63;

    // A-fragments: this wave's 64 codes (4 ctiles x 2 ksteps), bf16 hi only.
    const s16x8* Afr = (const s16x8*)(ws + AFR_OFF);
    s16x8 Ah[4][2];
    #pragma unroll
    for (int ct = 0; ct < 4; ++ct) {
        #pragma unroll
        for (int ks = 0; ks < 2; ++ks)
            Ah[ct][ks] = Afr[((w * 4 + ct) * 2 + ks) * 64 + l];
    }
    const float* en2b = (const float*)(ws + EN2B_OFF);
    f32x4 enf[4];
    #pragma unroll
    for (int ct = 0; ct < 4; ++ct) {
        const float4 t = *(const float4*)(en2b + w * 64 + ct * 16 + (l >> 4) * 4);
        enf[ct][0] = t.x; enf[ct][1] = t.y; enf[ct][2] = t.z; enf[ct][3] = t.w;
    }
    const int codebase = w * 64 + (l >> 4) * 4;

    const s16x8* Xf = (const s16x8*)xfrag;   // staged B-frags (coalesced reads)

    #pragma unroll 2
    for (int bt = 0; bt < 8; ++bt) {
        const int rt = bid * 8 + bt;
        const s16x8 bh0 = Xf[((rt * 2 + 0) * 2 + 0) * 64 + l];
        const s16x8 bh1 = Xf[((rt * 2 + 1) * 2 + 0) * 64 + l];
        const s16x8 bl0 = Xf[((rt * 2 + 0) * 2 + 1) * 64 + l];
        const s16x8 bl1 = Xf[((rt * 2 + 1) * 2 + 1) * 64 + l];

        unsigned m1 = 0xFFFFFFFFu, m2 = 0xFFFFFFFFu;
        #pragma unroll
        for (int ct = 0; ct < 4; ++ct) {
            f32x4 a = {0.f, 0.f, 0.f, 0.f};
            a = __builtin_amdgcn_mfma_f32_16x16x32_bf16(Ah[ct][0], bh0, a, 0, 0, 0);
            a = __builtin_amdgcn_mfma_f32_16x16x32_bf16(Ah[ct][1], bh1, a, 0, 0, 0);
            a = __builtin_amdgcn_mfma_f32_16x16x32_bf16(Ah[ct][0], bl0, a, 0, 0, 0);
            a = __builtin_amdgcn_mfma_f32_16x16x32_bf16(Ah[ct][1], bl1, a, 0, 0, 0);
            #pragma unroll
            for (int rg = 0; rg < 4; ++rg) {
                const float m = fmaf(-2.0f, a[rg], enf[ct][rg]);
                const unsigned u = (__float_as_uint(m) & 0xFFFFFE00u)
                                 | (unsigned)(codebase + ct * 16 + rg);
                const unsigned hi = m1 > u ? m1 : u;
                m1 = m1 < u ? m1 : u;
                m2 = m2 < hi ? m2 : hi;
            }
        }
        #pragma unroll
        for (int mask = 16; mask <= 32; mask <<= 1) {
            const unsigned o1 = __shfl_xor(m1, mask);
            const unsigned o2 = __shfl_xor(m2, mask);
            const unsigned hi  = m1 > o1 ? m1 : o1;
            const unsigned lo2 = m2 < o2 ? m2 : o2;
            m1 = m1 < o1 ? m1 : o1;
            m2 = hi < lo2 ? hi : lo2;
        }
        if (l < 16) sm_all[bt][w][l] = ((unsigned long long)m1 << 32) | m2;
    }
    __syncthreads();

    if (tid < 128) {
        const int bt = tid >> 4, c = tid & 15;
        unsigned long long p = sm_all[bt][0][c];
        unsigned m1 = (unsigned)(p >> 32), m2 = (unsigned)p;
        #pragma unroll
        for (int w2 = 1; w2 < 8; ++w2) {
            p = sm_all[bt][w2][c];
            const unsigned a1 = (unsigned)(p >> 32), a2 = (unsigned)p;
            const unsigned hi  = m1 > a1 ? m1 : a1;
            const unsigned lo2 = m2 < a2 ? m2 : a2;
            m1 = m1 < a1 ? m1 : a1;
            m2 = hi < lo2 ? hi : lo2;
        }
        const float f1 = __uint_as_float(m1 & 0xFFFFFE00u);
        const float f2 = __uint_as_float(m2 & 0xFFFFFE00u);
        pickf[bid * 128 + tid] =
            (unsigned short)((m1 & 0x1FFu) | ((f2 - f1 < TAU) ? 0x8000u : 0u));
    }
}

// ---------------- finish: fallback rescan of flagged rows + out/loss
__global__ __launch_bounds__(256, 4)
void vq_finish(const float* __restrict__ x, const char* __restrict__ ws,
               const unsigned short* __restrict__ pickf,
               float* __restrict__ out, double* __restrict__ loss_acc) {
    __shared__ unsigned spick[64];
    __shared__ unsigned char llist[64];
    __shared__ float fbuf[4][DIM];
    __shared__ double lpart[4];
    __shared__ int lcnt;

    const int tid = threadIdx.x, bid = blockIdx.x;
    const int w = __builtin_amdgcn_readfirstlane(tid >> 6);
    const int l = tid & 63;
    if (tid == 0) lcnt = 0;
    __syncthreads();

    if (tid < 64) {
        const unsigned p = pickf[bid * 64 + tid];
        spick[tid] = p & 0x1FFu;
        if (p & 0x8000u) { const int i = atomicAdd(&lcnt, 1); llist[i] = (unsigned char)tid; }
    }
    __syncthreads();

    // exact f32 rescan (round-2-identical arithmetic), one wave per flagged row,
    // row staged via LDS broadcast (round-8-validated, ~30 VGPRs live)
    {
        const float* eT  = (const float*)(ws + ET_OFF);
        const float* en2 = (const float*)(ws + EN2_OFF);
        const int nfb = lcnt;
        for (int i = w; i < nfb; i += 4) {
            const int r = llist[i];
            const int grow = bid * 64 + r;
            fbuf[w][l] = x[(size_t)grow * DIM + l];
            const float4* fr = (const float4*)fbuf[w];
            float4 a4 = make_float4(0.f, 0.f, 0.f, 0.f);
            #pragma unroll
            for (int j = 0; j < 16; ++j) {
                const float4 f = fr[j];
                a4.x = fmaf(f.x, f.x, a4.x);
                a4.y = fmaf(f.y, f.y, a4.y);
                a4.z = fmaf(f.z, f.z, a4.z);
                a4.w = fmaf(f.w, f.w, a4.w);
            }
            const float r2 = (a4.x + a4.y) + (a4.z + a4.w);
            unsigned long long best = 0xFFFFFFFFFFFFFFFFull;
            for (int c8 = 0; c8 < 8; ++c8) {
                const int k = l * 8 + c8;
                const float4* ek = (const float4*)(eT + k * DIM);
                float4 acc4 = make_float4(0.f, 0.f, 0.f, 0.f);
                #pragma unroll
                for (int j = 0; j < 16; ++j) {
                    const float4 e = ek[j];
                    const float4 f = fr[j];
                    acc4.x = fmaf(f.x, e.x, acc4.x);
                    acc4.y = fmaf(f.y, e.y, acc4.y);
                    acc4.z = fmaf(f.z, e.z, acc4.z);
                    acc4.w = fmaf(f.w, e.w, acc4.w);
                }
                const float dot = (acc4.x + acc4.y) + (acc4.z + acc4.w);
                const float s = (r2 + en2[k]) - 2.0f * dot;
                const unsigned long long pk =
                    ((unsigned long long)__float_as_uint(s) << 32) | (unsigned)k;
                if (pk < best) best = pk;   // ascending k + strict < == np.argmin
            }
            #pragma unroll
            for (int mask = 1; mask <= 32; mask <<= 1) {
                const unsigned long long o = __shfl_xor(best, mask);
                if (o < best) best = o;
            }
            if (l == 0) spick[r] = (unsigned)best & 0x1FFu;
        }
    }
    __syncthreads();

    // out = x + (q - x) and loss: thread <-> 64 contiguous bytes (coalesced)
    {
        const float* eT = (const float*)(ws + ET_OFF);
        const int r = tid >> 2, c4 = tid & 3;
        const int grow = bid * 64 + r;
        const float4* xr = (const float4*)(x + (size_t)grow * DIM) + c4 * 4;
        const float4* qr = (const float4*)(eT + spick[r] * DIM) + c4 * 4;
        float4* orow = ((float4*)out) + (size_t)grow * 16 + c4 * 4;
        float lsum = 0.0f;
        #pragma unroll
        for (int j = 0; j < 4; ++j) {
            const float4 q = qr[j], xv = xr[j];
            float4 o; float dx;
            dx = q.x - xv.x; o.x = xv.x + dx; lsum = fmaf(dx, dx, lsum);
            dx = q.y - xv.y; o.y = xv.y + dx; lsum = fmaf(dx, dx, lsum);
            dx = q.z - xv.z; o.z = xv.z + dx; lsum = fmaf(dx, dx, lsum);
            dx = q.w - xv.w; o.w = xv.w + dx; lsum = fmaf(dx, dx, lsum);
            orow[j] = o;
        }
        double dl = (double)lsum;
        #pragma unroll
        for (int off = 32; off > 0; off >>= 1) dl += __shfl_down(dl, off);
        if (l == 0) lpart[w] = dl;
    }
    __syncthreads();
    if (tid == 0) {
        double s = lpart[0] + lpart[1] + lpart[2] + lpart[3];
        atomicAdd(loss_acc, s);
    }
}

__global__ void vq_fin(const double* __restrict__ loss_acc, float* __restrict__ out) {
    if (threadIdx.x == 0)
        out[N_ROWS * DIM] = (float)(1.25 * loss_acc[0] * (1.0 / (double)(N_ROWS * DIM)));
}

extern "C" void kernel_launch(void* const* d_in, const int* in_sizes, int n_in,
                              void* d_out, int out_size, void* d_ws, size_t ws_size,
                              hipStream_t stream) {
    const float* x   = (const float*)d_in[0];
    const float* emb = (const float*)d_in[1];
    float* out = (float*)d_out;
    char*  ws  = (char*)d_ws;
    unsigned short* pickf = (unsigned short*)(ws + PICK_OFF);

    vq_prep<<<1026, 256, 0, stream>>>(x, emb, out, ws);
    vq_scan<<<512, 512, 0, stream>>>(out, ws, pickf);
    vq_finish<<<1024, 256, 0, stream>>>(x, ws, pickf, out, (double*)(ws + LOSS_OFF));
    vq_fin<<<1, 1, 0, stream>>>((const double*)(ws + LOSS_OFF), out);
}

// Round 11
// 93.396 us; speedup vs baseline: 1.2358x; 1.2235x over previous
//
#include <hip/hip_runtime.h>

// VectorQuantizer forward, phase-decoupled:
//   prep: codebook -> ws (eT f32, en2, en2b, bf16-hi A-frags); x -> bf16
//         hi/lo B-frags staged in d_out (round-5-validated layout)
//   scan: MFMA distance scan -> pick|flag u16 per row + compacted flag list
//   fb:   exact f32 rescan, ONE BLOCK PER FLAGGED ROW (2 codes/thread)
//   out:  streaming epilogue out = x + (q-x), loss
//   fin:  loss scalar
//
// Metric: argmin_k ||f-e_k||^2 == argmin_k (en2[k]-2 f.e_k). Approx dot =
// (fh+fl).eh (bf16), error sigma ~3e-4; TAU=6e-3 (validated rounds 7-10,
// absmax 0). Near-ties rescanned exactly with round-2-identical arithmetic.
// en2b = en2+6 keeps metric positive -> u32 bit-monotone pack, code idx in
// low 9 bits == np.argmin first-index tie-break.

#define N_ROWS 65536
#define DIM 64
#define KCODES 512

typedef short s16x8 __attribute__((ext_vector_type(8)));
typedef float f32x4 __attribute__((ext_vector_type(4)));

// ws byte offsets (total ~452 KB)
#define LOSS_OFF   0
#define FBCNT_OFF  64
#define EN2_OFF    256
#define EN2B_OFF   2304
#define ET_OFF     4352      // f32 codebook rows: 128 KB
#define AFR_OFF    135424    // bf16-hi A-frags: 64 KB
#define PICK_OFF   200960    // u16 pick|flag per row: 128 KB
#define FBLIST_OFF 332032    // u16 flagged-row list: 128 KB

#define TAU 6.0e-3f

__device__ __forceinline__ unsigned short f2bf(float f) {
    unsigned u = __float_as_uint(f);
    return (unsigned short)((u + 0x7fffu + ((u >> 16) & 1u)) >> 16);
}
__device__ __forceinline__ float bf2f(unsigned short h) {
    return __uint_as_float(((unsigned)h) << 16);
}

// ---------------- prep: blocks 0-1 codebook; blocks 2..1025 stage x-frags
__global__ void vq_prep(const float* __restrict__ x, const float* __restrict__ emb,
                        float* __restrict__ outbuf, char* __restrict__ ws) {
    const int bid = blockIdx.x, tid = threadIdx.x;
    if (bid < 2) {
        const int k = bid * 256 + tid;             // code 0..511
        if (k == 0) {
            *(double*)(ws + LOSS_OFF) = 0.0;
            *(int*)(ws + FBCNT_OFF) = 0;
        }
        float* en2  = (float*)(ws + EN2_OFF);
        float* en2b = (float*)(ws + EN2B_OFF);
        float* eT   = (float*)(ws + ET_OFF);
        uint4* Afr  = (uint4*)(ws + AFR_OFF);
        const int ctg = k >> 4, c = k & 15;
        float s = 0.0f;
        #pragma unroll
        for (int ks = 0; ks < 2; ++ks) {
            #pragma unroll
            for (int g = 0; g < 4; ++g) {
                unsigned short hb[8];
                #pragma unroll
                for (int j = 0; j < 8; ++j) {
                    const int d = ks * 32 + g * 8 + j;
                    const float v = emb[d * KCODES + k];   // coalesced across k
                    eT[k * DIM + d] = v;
                    s = fmaf(v, v, s);                     // same chain as round-2
                    hb[j] = f2bf(v);
                }
                uint4 H;
                H.x = hb[0] | ((unsigned)hb[1] << 16); H.y = hb[2] | ((unsigned)hb[3] << 16);
                H.z = hb[4] | ((unsigned)hb[5] << 16); H.w = hb[6] | ((unsigned)hb[7] << 16);
                Afr[(ctg * 2 + ks) * 64 + (g * 16 + c)] = H;
            }
        }
        en2[k] = s;
        en2b[k] = s + 6.0f;
    } else {
        // x -> fragment-ordered bf16 hi/lo in d_out (round-5-validated layout)
        const int rt   = (bid - 2) * 4 + (tid >> 6);   // row-tile 0..4095
        const int lane = tid & 63;
        const int row  = rt * 16 + (lane & 15);
        const int g    = lane >> 4;
        uint4* X = (uint4*)outbuf;
        #pragma unroll
        for (int ks = 0; ks < 2; ++ks) {
            const float* p = x + (size_t)row * DIM + ks * 32 + g * 8;
            const float4 v0 = *(const float4*)p;
            const float4 v1 = *(const float4*)(p + 4);
            float vv[8] = {v0.x, v0.y, v0.z, v0.w, v1.x, v1.y, v1.z, v1.w};
            unsigned short hb[8], lb[8];
            #pragma unroll
            for (int j = 0; j < 8; ++j) {
                const unsigned short h = f2bf(vv[j]);
                hb[j] = h;
                lb[j] = f2bf(vv[j] - bf2f(h));
            }
            uint4 H, L;
            H.x = hb[0] | ((unsigned)hb[1] << 16); H.y = hb[2] | ((unsigned)hb[3] << 16);
            H.z = hb[4] | ((unsigned)hb[5] << 16); H.w = hb[6] | ((unsigned)hb[7] << 16);
            L.x = lb[0] | ((unsigned)lb[1] << 16); L.y = lb[2] | ((unsigned)lb[3] << 16);
            L.z = lb[4] | ((unsigned)lb[5] << 16); L.w = lb[6] | ((unsigned)lb[7] << 16);
            X[((rt * 2 + ks) * 2 + 0) * 64 + lane] = H;
            X[((rt * 2 + ks) * 2 + 1) * 64 + lane] = L;
        }
    }
}

// ---------------- scan: picks + near-tie flags + compacted flag list
__global__ __launch_bounds__(512, 2)
void vq_scan(const float* __restrict__ xfrag, char* __restrict__ ws,
             unsigned short* __restrict__ pickf) {
    __shared__ unsigned long long sm_all[8][8][16];   // 8 KB

    const int tid = threadIdx.x;
    const int bid = blockIdx.x;
    const int w = __builtin_amdgcn_readfirstlane(tid >> 6);  // wave = 64-code group
    const int l = tid & 63;

    // A-fragments: this wave's 64 codes (4 ctiles x 2 ksteps), bf16 hi only.
    const s16x8* Afr = (const s16x8*)(ws + AFR_OFF);
    s16x8 Ah[4][2];
    #pragma unroll
    for (int ct = 0; ct < 4; ++ct) {
        #pragma unroll
        for (int ks = 0; ks < 2; ++ks)
            Ah[ct][ks] = Afr[((w * 4 + ct) * 2 + ks) * 64 + l];
    }
    const float* en2b = (const float*)(ws + EN2B_OFF);
    f32x4 enf[4];
    #pragma unroll
    for (int ct = 0; ct < 4; ++ct) {
        const float4 t = *(const float4*)(en2b + w * 64 + ct * 16 + (l >> 4) * 4);
        enf[ct][0] = t.x; enf[ct][1] = t.y; enf[ct][2] = t.z; enf[ct][3] = t.w;
    }
    const int codebase = w * 64 + (l >> 4) * 4;

    const s16x8* Xf = (const s16x8*)xfrag;   // staged B-frags (coalesced reads)

    #pragma unroll 2
    for (int bt = 0; bt < 8; ++bt) {
        const int rt = bid * 8 + bt;
        const s16x8 bh0 = Xf[((rt * 2 + 0) * 2 + 0) * 64 + l];
        const s16x8 bh1 = Xf[((rt * 2 + 1) * 2 + 0) * 64 + l];
        const s16x8 bl0 = Xf[((rt * 2 + 0) * 2 + 1) * 64 + l];
        const s16x8 bl1 = Xf[((rt * 2 + 1) * 2 + 1) * 64 + l];

        unsigned m1 = 0xFFFFFFFFu, m2 = 0xFFFFFFFFu;
        #pragma unroll
        for (int ct = 0; ct < 4; ++ct) {
            f32x4 a = {0.f, 0.f, 0.f, 0.f};
            a = __builtin_amdgcn_mfma_f32_16x16x32_bf16(Ah[ct][0], bh0, a, 0, 0, 0);
            a = __builtin_amdgcn_mfma_f32_16x16x32_bf16(Ah[ct][1], bh1, a, 0, 0, 0);
            a = __builtin_amdgcn_mfma_f32_16x16x32_bf16(Ah[ct][0], bl0, a, 0, 0, 0);
            a = __builtin_amdgcn_mfma_f32_16x16x32_bf16(Ah[ct][1], bl1, a, 0, 0, 0);
            #pragma unroll
            for (int rg = 0; rg < 4; ++rg) {
                const float m = fmaf(-2.0f, a[rg], enf[ct][rg]);
                const unsigned u = (__float_as_uint(m) & 0xFFFFFE00u)
                                 | (unsigned)(codebase + ct * 16 + rg);
                const unsigned hi = m1 > u ? m1 : u;
                m1 = m1 < u ? m1 : u;
                m2 = m2 < hi ? m2 : hi;
            }
        }
        #pragma unroll
        for (int mask = 16; mask <= 32; mask <<= 1) {
            const unsigned o1 = __shfl_xor(m1, mask);
            const unsigned o2 = __shfl_xor(m2, mask);
            const unsigned hi  = m1 > o1 ? m1 : o1;
            const unsigned lo2 = m2 < o2 ? m2 : o2;
            m1 = m1 < o1 ? m1 : o1;
            m2 = hi < lo2 ? hi : lo2;
        }
        if (l < 16) sm_all[bt][w][l] = ((unsigned long long)m1 << 32) | m2;
    }
    __syncthreads();

    if (tid < 128) {
        const int bt = tid >> 4, c = tid & 15;
        unsigned long long p = sm_all[bt][0][c];
        unsigned m1 = (unsigned)(p >> 32), m2 = (unsigned)p;
        #pragma unroll
        for (int w2 = 1; w2 < 8; ++w2) {
            p = sm_all[bt][w2][c];
            const unsigned a1 = (unsigned)(p >> 32), a2 = (unsigned)p;
            const unsigned hi  = m1 > a1 ? m1 : a1;
            const unsigned lo2 = m2 < a2 ? m2 : a2;
            m1 = m1 < a1 ? m1 : a1;
            m2 = hi < lo2 ? hi : lo2;
        }
        const float f1 = __uint_as_float(m1 & 0xFFFFFE00u);
        const float f2 = __uint_as_float(m2 & 0xFFFFFE00u);
        const int row = bid * 128 + tid;
        const bool flg = (f2 - f1 < TAU);
        pickf[row] = (unsigned short)((m1 & 0x1FFu) | (flg ? 0x8000u : 0u));
        if (flg) {
            const int i = atomicAdd((int*)(ws + FBCNT_OFF), 1);
            ((unsigned short*)(ws + FBLIST_OFF))[i] = (unsigned short)row;
        }
    }
}

// ---------------- fb: exact rescan, one block per flagged row, 2 codes/thread
__global__ __launch_bounds__(256, 4)
void vq_fb(const float* __restrict__ x, const char* __restrict__ ws,
           unsigned short* __restrict__ pickf) {
    __shared__ float fbuf[DIM];
    __shared__ unsigned long long wmin[4];

    const int tid = threadIdx.x;
    const int w = tid >> 6, l = tid & 63;
    const int nfb = *(const int*)(ws + FBCNT_OFF);
    const unsigned short* fblist = (const unsigned short*)(ws + FBLIST_OFF);
    const float* eT  = (const float*)(ws + ET_OFF);
    const float* en2 = (const float*)(ws + EN2_OFF);

    for (int i = blockIdx.x; i < nfb; i += gridDim.x) {
        const int row = fblist[i];
        __syncthreads();                         // protect fbuf/wmin reuse
        if (tid < 64) fbuf[tid] = x[(size_t)row * DIM + tid];
        __syncthreads();

        // r2 with round-2-identical chain (from LDS broadcast)
        const float4* fr = (const float4*)fbuf;
        float4 a4 = make_float4(0.f, 0.f, 0.f, 0.f);
        #pragma unroll
        for (int j = 0; j < 16; ++j) {
            const float4 f = fr[j];
            a4.x = fmaf(f.x, f.x, a4.x);
            a4.y = fmaf(f.y, f.y, a4.y);
            a4.z = fmaf(f.z, f.z, a4.z);
            a4.w = fmaf(f.w, f.w, a4.w);
        }
        const float r2 = (a4.x + a4.y) + (a4.z + a4.w);

        // 2 codes per thread, round-2-identical per-code chain
        unsigned long long best = 0xFFFFFFFFFFFFFFFFull;
        #pragma unroll
        for (int c = 0; c < 2; ++c) {
            const int k = tid * 2 + c;
            const float4* ek = (const float4*)(eT + k * DIM);
            float4 acc4 = make_float4(0.f, 0.f, 0.f, 0.f);
            #pragma unroll
            for (int j = 0; j < 16; ++j) {
                const float4 e = ek[j];
                const float4 f = fr[j];
                acc4.x = fmaf(f.x, e.x, acc4.x);
                acc4.y = fmaf(f.y, e.y, acc4.y);
                acc4.z = fmaf(f.z, e.z, acc4.z);
                acc4.w = fmaf(f.w, e.w, acc4.w);
            }
            const float dot = (acc4.x + acc4.y) + (acc4.z + acc4.w);
            const float s = (r2 + en2[k]) - 2.0f * dot;
            const unsigned long long pk =
                ((unsigned long long)__float_as_uint(s) << 32) | (unsigned)k;
            if (pk < best) best = pk;   // min + low-bits k == np.argmin order
        }
        #pragma unroll
        for (int mask = 1; mask <= 32; mask <<= 1) {
            const unsigned long long o = __shfl_xor(best, mask);
            if (o < best) best = o;
        }
        if (l == 0) wmin[w] = best;
        __syncthreads();
        if (tid == 0) {
            unsigned long long b = wmin[0];
            if (wmin[1] < b) b = wmin[1];
            if (wmin[2] < b) b = wmin[2];
            if (wmin[3] < b) b = wmin[3];
            pickf[row] = (unsigned short)(b & 0x1FFu);
        }
    }
}

// ---------------- out: streaming epilogue + loss
__global__ __launch_bounds__(256, 4)
void vq_out(const float* __restrict__ x, const char* __restrict__ ws,
            const unsigned short* __restrict__ pickf,
            float* __restrict__ out, double* __restrict__ loss_acc) {
    __shared__ double lpart[4];
    const int tid = threadIdx.x, bid = blockIdx.x;
    const int w = tid >> 6, l = tid & 63;

    const float* eT = (const float*)(ws + ET_OFF);
    const int r = tid >> 2, c4 = tid & 3;
    const int grow = bid * 64 + r;
    const unsigned pick = pickf[grow] & 0x1FFu;
    const float4* xr = (const float4*)(x + (size_t)grow * DIM) + c4 * 4;
    const float4* qr = (const float4*)(eT + pick * DIM) + c4 * 4;
    float4* orow = ((float4*)out) + (size_t)grow * 16 + c4 * 4;
    float lsum = 0.0f;
    #pragma unroll
    for (int j = 0; j < 4; ++j) {
        const float4 q = qr[j], xv = xr[j];
        float4 o; float dx;
        dx = q.x - xv.x; o.x = xv.x + dx; lsum = fmaf(dx, dx, lsum);
        dx = q.y - xv.y; o.y = xv.y + dx; lsum = fmaf(dx, dx, lsum);
        dx = q.z - xv.z; o.z = xv.z + dx; lsum = fmaf(dx, dx, lsum);
        dx = q.w - xv.w; o.w = xv.w + dx; lsum = fmaf(dx, dx, lsum);
        orow[j] = o;
    }
    double dl = (double)lsum;
    #pragma unroll
    for (int off = 32; off > 0; off >>= 1) dl += __shfl_down(dl, off);
    if (l == 0) lpart[w] = dl;
    __syncthreads();
    if (tid == 0) {
        const double s = (lpart[0] + lpart[1]) + (lpart[2] + lpart[3]);
        atomicAdd(loss_acc, s);
    }
}

__global__ void vq_fin(const double* __restrict__ loss_acc, float* __restrict__ out) {
    if (threadIdx.x == 0)
        out[N_ROWS * DIM] = (float)(1.25 * loss_acc[0] * (1.0 / (double)(N_ROWS * DIM)));
}

extern "C" void kernel_launch(void* const* d_in, const int* in_sizes, int n_in,
                              void* d_out, int out_size, void* d_ws, size_t ws_size,
                              hipStream_t stream) {
    const float* x   = (const float*)d_in[0];
    const float* emb = (const float*)d_in[1];
    float* out = (float*)d_out;
    char*  ws  = (char*)d_ws;
    unsigned short* pickf = (unsigned short*)(ws + PICK_OFF);

    vq_prep<<<1026, 256, 0, stream>>>(x, emb, out, ws);
    vq_scan<<<512, 512, 0, stream>>>(out, ws, pickf);
    vq_fb<<<1024, 256, 0, stream>>>(x, ws, pickf);
    vq_out<<<1024, 256, 0, stream>>>(x, ws, pickf, out, (double*)(ws + LOSS_OFF));
    vq_fin<<<1, 1, 0, stream>>>((const double*)(ws + LOSS_OFF), out);
}

// Round 12
// 63.347 us; speedup vs baseline: 1.8220x; 1.4744x over previous
//
#include <hip/hip_runtime.h>

// VectorQuantizer forward, phase-decoupled:
//   prep: codebook -> ws (eT f32, en2, en2b, bf16 hi+lo A-frags); x -> bf16
//         hi/lo B-frags staged in d_out (round-5-validated layout)
//   scan: MFMA distance scan (3-term bf16 split, round-5-validated) ->
//         pick|flag u16 per row + compacted flag list
//   fb:   exact f32 rescan, one block per flagged row (2 codes/thread)
//   out:  streaming epilogue out = x + (q-x), loss
//   fin:  loss scalar
//
// Metric: argmin_k ||f-e_k||^2 == argmin_k (en2[k]-2 f.e_k). Approx dot =
// fh.eh + fh.el + fl.eh (bf16 splits), residual = fl.el, sigma ~4e-6;
// TAU=1.2e-3 (round-5-validated, absmax 0) >> 100 sigma + mask quantum.
// Near-ties rescanned exactly with round-2-identical arithmetic.
// en2b = en2+6 keeps metric positive -> u32 bit-monotone pack, code idx in
// low 9 bits == np.argmin first-index tie-break.

#define N_ROWS 65536
#define DIM 64
#define KCODES 512

typedef short s16x8 __attribute__((ext_vector_type(8)));
typedef float f32x4 __attribute__((ext_vector_type(4)));

// ws byte offsets (total ~460 KB)
#define LOSS_OFF   0
#define FBCNT_OFF  64
#define EN2_OFF    256
#define EN2B_OFF   2304
#define ET_OFF     4352      // f32 codebook rows: 128 KB
#define AFR_OFF    135424    // bf16 hi+lo A-frags: 128 KB
#define PICK_OFF   266496    // u16 pick|flag per row: 128 KB
#define FBLIST_OFF 397568    // u16 flagged-row list: 128 KB

#define TAU 1.2e-3f

__device__ __forceinline__ unsigned short f2bf(float f) {
    unsigned u = __float_as_uint(f);
    return (unsigned short)((u + 0x7fffu + ((u >> 16) & 1u)) >> 16);
}
__device__ __forceinline__ float bf2f(unsigned short h) {
    return __uint_as_float(((unsigned)h) << 16);
}

// ---------------- prep: blocks 0-1 codebook; blocks 2..1025 stage x-frags
__global__ void vq_prep(const float* __restrict__ x, const float* __restrict__ emb,
                        float* __restrict__ outbuf, char* __restrict__ ws) {
    const int bid = blockIdx.x, tid = threadIdx.x;
    if (bid < 2) {
        const int k = bid * 256 + tid;             // code 0..511
        if (k == 0) {
            *(double*)(ws + LOSS_OFF) = 0.0;
            *(int*)(ws + FBCNT_OFF) = 0;
        }
        float* en2  = (float*)(ws + EN2_OFF);
        float* en2b = (float*)(ws + EN2B_OFF);
        float* eT   = (float*)(ws + ET_OFF);
        uint4* Afr  = (uint4*)(ws + AFR_OFF);
        const int ctg = k >> 4, c = k & 15;
        float s = 0.0f;
        #pragma unroll
        for (int ks = 0; ks < 2; ++ks) {
            #pragma unroll
            for (int g = 0; g < 4; ++g) {
                unsigned short hb[8], lb[8];
                #pragma unroll
                for (int j = 0; j < 8; ++j) {
                    const int d = ks * 32 + g * 8 + j;
                    const float v = emb[d * KCODES + k];   // coalesced across k
                    eT[k * DIM + d] = v;
                    s = fmaf(v, v, s);                     // same chain as round-2
                    const unsigned short h = f2bf(v);
                    hb[j] = h;
                    lb[j] = f2bf(v - bf2f(h));
                }
                uint4 H, L;
                H.x = hb[0] | ((unsigned)hb[1] << 16); H.y = hb[2] | ((unsigned)hb[3] << 16);
                H.z = hb[4] | ((unsigned)hb[5] << 16); H.w = hb[6] | ((unsigned)hb[7] << 16);
                L.x = lb[0] | ((unsigned)lb[1] << 16); L.y = lb[2] | ((unsigned)lb[3] << 16);
                L.z = lb[4] | ((unsigned)lb[5] << 16); L.w = lb[6] | ((unsigned)lb[7] << 16);
                const int lane = g * 16 + c;
                Afr[((ctg * 2 + ks) * 2 + 0) * 64 + lane] = H;   // hi
                Afr[((ctg * 2 + ks) * 2 + 1) * 64 + lane] = L;   // lo
            }
        }
        en2[k] = s;
        en2b[k] = s + 6.0f;
    } else {
        // x -> fragment-ordered bf16 hi/lo in d_out (round-5-validated layout)
        const int rt   = (bid - 2) * 4 + (tid >> 6);   // row-tile 0..4095
        const int lane = tid & 63;
        const int row  = rt * 16 + (lane & 15);
        const int g    = lane >> 4;
        uint4* X = (uint4*)outbuf;
        #pragma unroll
        for (int ks = 0; ks < 2; ++ks) {
            const float* p = x + (size_t)row * DIM + ks * 32 + g * 8;
            const float4 v0 = *(const float4*)p;
            const float4 v1 = *(const float4*)(p + 4);
            float vv[8] = {v0.x, v0.y, v0.z, v0.w, v1.x, v1.y, v1.z, v1.w};
            unsigned short hb[8], lb[8];
            #pragma unroll
            for (int j = 0; j < 8; ++j) {
                const unsigned short h = f2bf(vv[j]);
                hb[j] = h;
                lb[j] = f2bf(vv[j] - bf2f(h));
            }
            uint4 H, L;
            H.x = hb[0] | ((unsigned)hb[1] << 16); H.y = hb[2] | ((unsigned)hb[3] << 16);
            H.z = hb[4] | ((unsigned)hb[5] << 16); H.w = hb[6] | ((unsigned)hb[7] << 16);
            L.x = lb[0] | ((unsigned)lb[1] << 16); L.y = lb[2] | ((unsigned)lb[3] << 16);
            L.z = lb[4] | ((unsigned)lb[5] << 16); L.w = lb[6] | ((unsigned)lb[7] << 16);
            X[((rt * 2 + ks) * 2 + 0) * 64 + lane] = H;
            X[((rt * 2 + ks) * 2 + 1) * 64 + lane] = L;
        }
    }
}

// ---------------- scan: picks + near-tie flags + compacted flag list
__global__ __launch_bounds__(512, 2)
void vq_scan(const float* __restrict__ xfrag, char* __restrict__ ws,
             unsigned short* __restrict__ pickf) {
    __shared__ unsigned long long sm_all[8][8][16];   // 8 KB

    const int tid = threadIdx.x;
    const int bid = blockIdx.x;
    const int w = __builtin_amdgcn_readfirstlane(tid >> 6);  // wave = 64-code group
    const int l = tid & 63;

    // A-fragments: this wave's 64 codes (4 ctiles x 2 ksteps), bf16 hi+lo.
    const s16x8* Afr = (const s16x8*)(ws + AFR_OFF);
    s16x8 Aeh[4][2], Ael[4][2];
    #pragma unroll
    for (int ct = 0; ct < 4; ++ct) {
        #pragma unroll
        for (int ks = 0; ks < 2; ++ks) {
            const int ctg = w * 4 + ct;
            Aeh[ct][ks] = Afr[((ctg * 2 + ks) * 2 + 0) * 64 + l];
            Ael[ct][ks] = Afr[((ctg * 2 + ks) * 2 + 1) * 64 + l];
        }
    }
    const float* en2b = (const float*)(ws + EN2B_OFF);
    f32x4 enf[4];
    #pragma unroll
    for (int ct = 0; ct < 4; ++ct) {
        const float4 t = *(const float4*)(en2b + w * 64 + ct * 16 + (l >> 4) * 4);
        enf[ct][0] = t.x; enf[ct][1] = t.y; enf[ct][2] = t.z; enf[ct][3] = t.w;
    }
    const int codebase = w * 64 + (l >> 4) * 4;

    const s16x8* Xf = (const s16x8*)xfrag;   // staged B-frags (coalesced reads)

    #pragma unroll 2
    for (int bt = 0; bt < 8; ++bt) {
        const int rt = bid * 8 + bt;
        const s16x8 bh0 = Xf[((rt * 2 + 0) * 2 + 0) * 64 + l];
        const s16x8 bh1 = Xf[((rt * 2 + 1) * 2 + 0) * 64 + l];
        const s16x8 bl0 = Xf[((rt * 2 + 0) * 2 + 1) * 64 + l];
        const s16x8 bl1 = Xf[((rt * 2 + 1) * 2 + 1) * 64 + l];

        unsigned m1 = 0xFFFFFFFFu, m2 = 0xFFFFFFFFu;
        #pragma unroll
        for (int ct = 0; ct < 4; ++ct) {
            f32x4 a = {0.f, 0.f, 0.f, 0.f};
            a = __builtin_amdgcn_mfma_f32_16x16x32_bf16(Aeh[ct][0], bh0, a, 0, 0, 0);
            a = __builtin_amdgcn_mfma_f32_16x16x32_bf16(Aeh[ct][1], bh1, a, 0, 0, 0);
            a = __builtin_amdgcn_mfma_f32_16x16x32_bf16(Ael[ct][0], bh0, a, 0, 0, 0);
            a = __builtin_amdgcn_mfma_f32_16x16x32_bf16(Ael[ct][1], bh1, a, 0, 0, 0);
            a = __builtin_amdgcn_mfma_f32_16x16x32_bf16(Aeh[ct][0], bl0, a, 0, 0, 0);
            a = __builtin_amdgcn_mfma_f32_16x16x32_bf16(Aeh[ct][1], bl1, a, 0, 0, 0);
            #pragma unroll
            for (int rg = 0; rg < 4; ++rg) {
                const float m = fmaf(-2.0f, a[rg], enf[ct][rg]);
                const unsigned u = (__float_as_uint(m) & 0xFFFFFE00u)
                                 | (unsigned)(codebase + ct * 16 + rg);
                const unsigned hi = m1 > u ? m1 : u;
                m1 = m1 < u ? m1 : u;
                m2 = m2 < hi ? m2 : hi;
            }
        }
        #pragma unroll
        for (int mask = 16; mask <= 32; mask <<= 1) {
            const unsigned o1 = __shfl_xor(m1, mask);
            const unsigned o2 = __shfl_xor(m2, mask);
            const unsigned hi  = m1 > o1 ? m1 : o1;
            const unsigned lo2 = m2 < o2 ? m2 : o2;
            m1 = m1 < o1 ? m1 : o1;
            m2 = hi < lo2 ? hi : lo2;
        }
        if (l < 16) sm_all[bt][w][l] = ((unsigned long long)m1 << 32) | m2;
    }
    __syncthreads();

    if (tid < 128) {
        const int bt = tid >> 4, c = tid & 15;
        unsigned long long p = sm_all[bt][0][c];
        unsigned m1 = (unsigned)(p >> 32), m2 = (unsigned)p;
        #pragma unroll
        for (int w2 = 1; w2 < 8; ++w2) {
            p = sm_all[bt][w2][c];
            const unsigned a1 = (unsigned)(p >> 32), a2 = (unsigned)p;
            const unsigned hi  = m1 > a1 ? m1 : a1;
            const unsigned lo2 = m2 < a2 ? m2 : a2;
            m1 = m1 < a1 ? m1 : a1;
            m2 = hi < lo2 ? hi : lo2;
        }
        const float f1 = __uint_as_float(m1 & 0xFFFFFE00u);
        const float f2 = __uint_as_float(m2 & 0xFFFFFE00u);
        const int row = bid * 128 + tid;
        const bool flg = (f2 - f1 < TAU);
        pickf[row] = (unsigned short)((m1 & 0x1FFu) | (flg ? 0x8000u : 0u));
        if (flg) {
            const int i = atomicAdd((int*)(ws + FBCNT_OFF), 1);
            ((unsigned short*)(ws + FBLIST_OFF))[i] = (unsigned short)row;
        }
    }
}

// ---------------- fb: exact rescan, one block per flagged row, 2 codes/thread
__global__ __launch_bounds__(256, 2)
void vq_fb(const float* __restrict__ x, const char* __restrict__ ws,
           unsigned short* __restrict__ pickf) {
    __shared__ float fbuf[DIM];
    __shared__ unsigned long long wmin[4];

    const int tid = threadIdx.x;
    const int w = tid >> 6, l = tid & 63;
    const int nfb = *(const int*)(ws + FBCNT_OFF);
    const unsigned short* fblist = (const unsigned short*)(ws + FBLIST_OFF);
    const float* eT  = (const float*)(ws + ET_OFF);
    const float* en2 = (const float*)(ws + EN2_OFF);

    for (int i = blockIdx.x; i < nfb; i += gridDim.x) {
        const int row = fblist[i];
        __syncthreads();                         // protect fbuf/wmin reuse
        if (tid < 64) fbuf[tid] = x[(size_t)row * DIM + tid];
        __syncthreads();

        // r2 with round-2-identical chain (from LDS broadcast)
        const float4* fr = (const float4*)fbuf;
        float4 a4 = make_float4(0.f, 0.f, 0.f, 0.f);
        #pragma unroll
        for (int j = 0; j < 16; ++j) {
            const float4 f = fr[j];
            a4.x = fmaf(f.x, f.x, a4.x);
            a4.y = fmaf(f.y, f.y, a4.y);
            a4.z = fmaf(f.z, f.z, a4.z);
            a4.w = fmaf(f.w, f.w, a4.w);
        }
        const float r2 = (a4.x + a4.y) + (a4.z + a4.w);

        // 2 codes per thread, round-2-identical per-code chain
        unsigned long long best = 0xFFFFFFFFFFFFFFFFull;
        #pragma unroll
        for (int c = 0; c < 2; ++c) {
            const int k = tid * 2 + c;
            const float4* ek = (const float4*)(eT + k * DIM);
            float4 acc4 = make_float4(0.f, 0.f, 0.f, 0.f);
            #pragma unroll
            for (int j = 0; j < 16; ++j) {
                const float4 e = ek[j];
                const float4 f = fr[j];
                acc4.x = fmaf(f.x, e.x, acc4.x);
                acc4.y = fmaf(f.y, e.y, acc4.y);
                acc4.z = fmaf(f.z, e.z, acc4.z);
                acc4.w = fmaf(f.w, e.w, acc4.w);
            }
            const float dot = (acc4.x + acc4.y) + (acc4.z + acc4.w);
            const float s = (r2 + en2[k]) - 2.0f * dot;
            const unsigned long long pk =
                ((unsigned long long)__float_as_uint(s) << 32) | (unsigned)k;
            if (pk < best) best = pk;   // min + low-bits k == np.argmin order
        }
        #pragma unroll
        for (int mask = 1; mask <= 32; mask <<= 1) {
            const unsigned long long o = __shfl_xor(best, mask);
            if (o < best) best = o;
        }
        if (l == 0) wmin[w] = best;
        __syncthreads();
        if (tid == 0) {
            unsigned long long b = wmin[0];
            if (wmin[1] < b) b = wmin[1];
            if (wmin[2] < b) b = wmin[2];
            if (wmin[3] < b) b = wmin[3];
            pickf[row] = (unsigned short)(b & 0x1FFu);
        }
    }
}

// ---------------- out: streaming epilogue + loss
__global__ __launch_bounds__(256, 4)
void vq_out(const float* __restrict__ x, const char* __restrict__ ws,
            const unsigned short* __restrict__ pickf,
            float* __restrict__ out, double* __restrict__ loss_acc) {
    __shared__ double lpart[4];
    const int tid = threadIdx.x, bid = blockIdx.x;
    const int w = tid >> 6, l = tid & 63;

    const float* eT = (const float*)(ws + ET_OFF);
    const int r = tid >> 2, c4 = tid & 3;
    const int grow = bid * 64 + r;
    const unsigned pick = pickf[grow] & 0x1FFu;
    const float4* xr = (const float4*)(x + (size_t)grow * DIM) + c4 * 4;
    const float4* qr = (const float4*)(eT + pick * DIM) + c4 * 4;
    float4* orow = ((float4*)out) + (size_t)grow * 16 + c4 * 4;
    float lsum = 0.0f;
    #pragma unroll
    for (int j = 0; j < 4; ++j) {
        const float4 q = qr[j], xv = xr[j];
        float4 o; float dx;
        dx = q.x - xv.x; o.x = xv.x + dx; lsum = fmaf(dx, dx, lsum);
        dx = q.y - xv.y; o.y = xv.y + dx; lsum = fmaf(dx, dx, lsum);
        dx = q.z - xv.z; o.z = xv.z + dx; lsum = fmaf(dx, dx, lsum);
        dx = q.w - xv.w; o.w = xv.w + dx; lsum = fmaf(dx, dx, lsum);
        orow[j] = o;
    }
    double dl = (double)lsum;
    #pragma unroll
    for (int off = 32; off > 0; off >>= 1) dl += __shfl_down(dl, off);
    if (l == 0) lpart[w] = dl;
    __syncthreads();
    if (tid == 0) {
        const double s = (lpart[0] + lpart[1]) + (lpart[2] + lpart[3]);
        atomicAdd(loss_acc, s);
    }
}

__global__ void vq_fin(const double* __restrict__ loss_acc, float* __restrict__ out) {
    if (threadIdx.x == 0)
        out[N_ROWS * DIM] = (float)(1.25 * loss_acc[0] * (1.0 / (double)(N_ROWS * DIM)));
}

extern "C" void kernel_launch(void* const* d_in, const int* in_sizes, int n_in,
                              void* d_out, int out_size, void* d_ws, size_t ws_size,
                              hipStream_t stream) {
    const float* x   = (const float*)d_in[0];
    const float* emb = (const float*)d_in[1];
    float* out = (float*)d_out;
    char*  ws  = (char*)d_ws;
    unsigned short* pickf = (unsigned short*)(ws + PICK_OFF);

    vq_prep<<<1026, 256, 0, stream>>>(x, emb, out, ws);
    vq_scan<<<512, 512, 0, stream>>>(out, ws, pickf);
    vq_fb<<<512, 256, 0, stream>>>(x, ws, pickf);
    vq_out<<<1024, 256, 0, stream>>>(x, ws, pickf, out, (double*)(ws + LOSS_OFF));
    vq_fin<<<1, 1, 0, stream>>>((const double*)(ws + LOSS_OFF), out);
}

// Round 13
// 54.356 us; speedup vs baseline: 2.1233x; 1.1654x over previous
//
#include <hip/hip_runtime.h>

// VectorQuantizer forward, fused 3-launch structure:
//   prep: codebook -> ws (eT f32, en2, en2b, bf16 hi+lo A-frags)  [2 blocks]
//   main: per block of 128 rows: x->bf16 cvt in-register (round-6-validated),
//         3-term bf16 MFMA scan (round-12-validated), block-local exact
//         rescan of near-ties (round-2-identical chain), streaming epilogue
//   fin:  loss scalar
//
// Metric: argmin_k ||f-e_k||^2 == argmin_k (en2[k]-2 f.e_k). Approx dot =
// fh.eh + fh.el + fl.eh (bf16 splits), residual fl.el sigma ~4e-6;
// TAU=1.2e-3 (validated rounds 5/12, absmax 0). en2b = en2+6 keeps the
// metric positive -> u32 bit-monotone pack, code idx in low 9 bits ==
// np.argmin first-index tie-break.

#define N_ROWS 65536
#define DIM 64
#define KCODES 512
#define ROWS_PER_BLOCK 128
#define THREADS 512

typedef short s16x8 __attribute__((ext_vector_type(8)));
typedef float f32x4 __attribute__((ext_vector_type(4)));

// ws byte offsets
#define LOSS_OFF   0
#define EN2_OFF    256
#define EN2B_OFF   2304
#define ET_OFF     4352      // f32 codebook rows: 128 KB
#define AFR_OFF    135424    // bf16 hi+lo A-frags: 128 KB

#define TAU 1.2e-3f

__device__ __forceinline__ unsigned short f2bf(float f) {
    unsigned u = __float_as_uint(f);
    return (unsigned short)((u + 0x7fffu + ((u >> 16) & 1u)) >> 16);
}
__device__ __forceinline__ float bf2f(unsigned short h) {
    return __uint_as_float(((unsigned)h) << 16);
}
__device__ __forceinline__ void cvt8(const float* __restrict__ p,
                                     s16x8& hi, s16x8& lo) {
    const float4 v0 = *(const float4*)p;
    const float4 v1 = *(const float4*)(p + 4);
    const float vv[8] = {v0.x, v0.y, v0.z, v0.w, v1.x, v1.y, v1.z, v1.w};
    #pragma unroll
    for (int j = 0; j < 8; ++j) {
        const unsigned short h = f2bf(vv[j]);
        hi[j] = (short)h;
        lo[j] = (short)f2bf(vv[j] - bf2f(h));
    }
}

// ---------------- prep: codebook only (2 blocks x 256 threads)
__global__ void vq_prep(const float* __restrict__ emb, char* __restrict__ ws) {
    const int k = blockIdx.x * 256 + threadIdx.x;   // code 0..511
    if (k == 0) *(double*)(ws + LOSS_OFF) = 0.0;
    float* en2  = (float*)(ws + EN2_OFF);
    float* en2b = (float*)(ws + EN2B_OFF);
    float* eT   = (float*)(ws + ET_OFF);
    uint4* Afr  = (uint4*)(ws + AFR_OFF);
    const int ctg = k >> 4, c = k & 15;
    float s = 0.0f;
    #pragma unroll
    for (int ks = 0; ks < 2; ++ks) {
        #pragma unroll
        for (int g = 0; g < 4; ++g) {
            unsigned short hb[8], lb[8];
            #pragma unroll
            for (int j = 0; j < 8; ++j) {
                const int d = ks * 32 + g * 8 + j;
                const float v = emb[d * KCODES + k];   // coalesced across k
                eT[k * DIM + d] = v;
                s = fmaf(v, v, s);                     // same chain as round-2
                const unsigned short h = f2bf(v);
                hb[j] = h;
                lb[j] = f2bf(v - bf2f(h));
            }
            uint4 H, L;
            H.x = hb[0] | ((unsigned)hb[1] << 16); H.y = hb[2] | ((unsigned)hb[3] << 16);
            H.z = hb[4] | ((unsigned)hb[5] << 16); H.w = hb[6] | ((unsigned)hb[7] << 16);
            L.x = lb[0] | ((unsigned)lb[1] << 16); L.y = lb[2] | ((unsigned)lb[3] << 16);
            L.z = lb[4] | ((unsigned)lb[5] << 16); L.w = lb[6] | ((unsigned)lb[7] << 16);
            const int lane = g * 16 + c;
            Afr[((ctg * 2 + ks) * 2 + 0) * 64 + lane] = H;   // hi
            Afr[((ctg * 2 + ks) * 2 + 1) * 64 + lane] = L;   // lo
        }
    }
    en2[k] = s;
    en2b[k] = s + 6.0f;
}

// ---------------- main: cvt + scan + rescan + epilogue
__global__ __launch_bounds__(THREADS, 2)
void vq_main(const float* __restrict__ x, const char* __restrict__ ws,
             float* __restrict__ out, double* __restrict__ loss_acc) {
    __shared__ unsigned long long sm_all[8][8][16];   // 8 KB
    __shared__ unsigned pick[ROWS_PER_BLOCK];
    __shared__ unsigned char llist[ROWS_PER_BLOCK];
    __shared__ float fbuf[DIM];
    __shared__ unsigned long long wmin[8];
    __shared__ double lpart[8];
    __shared__ int lcnt;

    const int tid = threadIdx.x;
    const int bid = blockIdx.x;
    const int w = __builtin_amdgcn_readfirstlane(tid >> 6);  // wave = 64-code group
    const int l = tid & 63;
    if (tid == 0) lcnt = 0;

    // A-fragments: this wave's 64 codes (4 ctiles x 2 ksteps), bf16 hi+lo.
    const s16x8* Afr = (const s16x8*)(ws + AFR_OFF);
    s16x8 Aeh[4][2], Ael[4][2];
    #pragma unroll
    for (int ct = 0; ct < 4; ++ct) {
        #pragma unroll
        for (int ks = 0; ks < 2; ++ks) {
            const int ctg = w * 4 + ct;
            Aeh[ct][ks] = Afr[((ctg * 2 + ks) * 2 + 0) * 64 + l];
            Ael[ct][ks] = Afr[((ctg * 2 + ks) * 2 + 1) * 64 + l];
        }
    }
    const float* en2b = (const float*)(ws + EN2B_OFF);
    f32x4 enf[4];
    #pragma unroll
    for (int ct = 0; ct < 4; ++ct) {
        const float4 t = *(const float4*)(en2b + w * 64 + ct * 16 + (l >> 4) * 4);
        enf[ct][0] = t.x; enf[ct][1] = t.y; enf[ct][2] = t.z; enf[ct][3] = t.w;
    }
    const int codebase = w * 64 + (l >> 4) * 4;

    // Phase 1: scan 8 row-tiles; B-frags converted in-register from x
    // (round-6-validated bit-identical to the staged path).
    #pragma unroll 2
    for (int bt = 0; bt < 8; ++bt) {
        const int rowb = bid * ROWS_PER_BLOCK + bt * 16 + (l & 15);
        const float* px = x + (size_t)rowb * DIM + (l >> 4) * 8;
        s16x8 bh0, bl0, bh1, bl1;
        cvt8(px, bh0, bl0);
        cvt8(px + 32, bh1, bl1);

        unsigned m1 = 0xFFFFFFFFu, m2 = 0xFFFFFFFFu;
        #pragma unroll
        for (int ct = 0; ct < 4; ++ct) {
            f32x4 a = {0.f, 0.f, 0.f, 0.f};
            a = __builtin_amdgcn_mfma_f32_16x16x32_bf16(Aeh[ct][0], bh0, a, 0, 0, 0);
            a = __builtin_amdgcn_mfma_f32_16x16x32_bf16(Aeh[ct][1], bh1, a, 0, 0, 0);
            a = __builtin_amdgcn_mfma_f32_16x16x32_bf16(Ael[ct][0], bh0, a, 0, 0, 0);
            a = __builtin_amdgcn_mfma_f32_16x16x32_bf16(Ael[ct][1], bh1, a, 0, 0, 0);
            a = __builtin_amdgcn_mfma_f32_16x16x32_bf16(Aeh[ct][0], bl0, a, 0, 0, 0);
            a = __builtin_amdgcn_mfma_f32_16x16x32_bf16(Aeh[ct][1], bl1, a, 0, 0, 0);
            #pragma unroll
            for (int rg = 0; rg < 4; ++rg) {
                const float m = fmaf(-2.0f, a[rg], enf[ct][rg]);
                const unsigned u = (__float_as_uint(m) & 0xFFFFFE00u)
                                 | (unsigned)(codebase + ct * 16 + rg);
                const unsigned hi = m1 > u ? m1 : u;
                m1 = m1 < u ? m1 : u;
                m2 = m2 < hi ? m2 : hi;
            }
        }
        #pragma unroll
        for (int mask = 16; mask <= 32; mask <<= 1) {
            const unsigned o1 = __shfl_xor(m1, mask);
            const unsigned o2 = __shfl_xor(m2, mask);
            const unsigned hi  = m1 > o1 ? m1 : o1;
            const unsigned lo2 = m2 < o2 ? m2 : o2;
            m1 = m1 < o1 ? m1 : o1;
            m2 = hi < lo2 ? hi : lo2;
        }
        if (l < 16) sm_all[bt][w][l] = ((unsigned long long)m1 << 32) | m2;
    }
    __syncthreads();

    // Phase 2: combine 8 waves per row; flag near-ties (block-local list).
    if (tid < ROWS_PER_BLOCK) {
        const int bt = tid >> 4, c = tid & 15;
        unsigned long long p = sm_all[bt][0][c];
        unsigned m1 = (unsigned)(p >> 32), m2 = (unsigned)p;
        #pragma unroll
        for (int w2 = 1; w2 < 8; ++w2) {
            p = sm_all[bt][w2][c];
            const unsigned a1 = (unsigned)(p >> 32), a2 = (unsigned)p;
            const unsigned hi  = m1 > a1 ? m1 : a1;
            const unsigned lo2 = m2 < a2 ? m2 : a2;
            m1 = m1 < a1 ? m1 : a1;
            m2 = hi < lo2 ? hi : lo2;
        }
        pick[tid] = m1 & 0x1FFu;
        const float f1 = __uint_as_float(m1 & 0xFFFFFE00u);
        const float f2 = __uint_as_float(m2 & 0xFFFFFE00u);
        if (f2 - f1 < TAU) {
            const int i = atomicAdd(&lcnt, 1);
            llist[i] = (unsigned char)tid;
        }
    }
    __syncthreads();

    // Phase 3: exact f32 rescan of flagged rows, block-parallel (1 code/thread,
    // round-2-identical per-code chain; u64 min == np.argmin tie-break).
    {
        const float* eT  = (const float*)(ws + ET_OFF);
        const float* en2 = (const float*)(ws + EN2_OFF);
        const int nfb = lcnt;
        for (int i = 0; i < nfb; ++i) {
            const int r = llist[i];
            const int grow = bid * ROWS_PER_BLOCK + r;
            if (tid < 64) fbuf[tid] = x[(size_t)grow * DIM + tid];
            __syncthreads();

            const float4* fr = (const float4*)fbuf;
            float4 a4 = make_float4(0.f, 0.f, 0.f, 0.f);
            #pragma unroll
            for (int j = 0; j < 16; ++j) {
                const float4 f = fr[j];
                a4.x = fmaf(f.x, f.x, a4.x);
                a4.y = fmaf(f.y, f.y, a4.y);
                a4.z = fmaf(f.z, f.z, a4.z);
                a4.w = fmaf(f.w, f.w, a4.w);
            }
            const float r2 = (a4.x + a4.y) + (a4.z + a4.w);

            const int k = tid;   // one code per thread
            const float4* ek = (const float4*)(eT + k * DIM);
            float4 acc4 = make_float4(0.f, 0.f, 0.f, 0.f);
            #pragma unroll
            for (int j = 0; j < 16; ++j) {
                const float4 e = ek[j];
                const float4 f = fr[j];
                acc4.x = fmaf(f.x, e.x, acc4.x);
                acc4.y = fmaf(f.y, e.y, acc4.y);
                acc4.z = fmaf(f.z, e.z, acc4.z);
                acc4.w = fmaf(f.w, e.w, acc4.w);
            }
            const float dot = (acc4.x + acc4.y) + (acc4.z + acc4.w);
            const float s = (r2 + en2[k]) - 2.0f * dot;
            unsigned long long best =
                ((unsigned long long)__float_as_uint(s) << 32) | (unsigned)k;
            #pragma unroll
            for (int mask = 1; mask <= 32; mask <<= 1) {
                const unsigned long long o = __shfl_xor(best, mask);
                if (o < best) best = o;
            }
            if (l == 0) wmin[w] = best;
            __syncthreads();
            if (tid == 0) {
                unsigned long long b = wmin[0];
                #pragma unroll
                for (int t = 1; t < 8; ++t) if (wmin[t] < b) b = wmin[t];
                pick[r] = (unsigned)(b & 0x1FFu);
            }
            __syncthreads();
        }
    }
    __syncthreads();

    // Phase 4: out = x + (q - x) and loss (4 threads per row, x re-read L2-hot)
    {
        const float* eT = (const float*)(ws + ET_OFF);
        const int r = tid >> 2, c4 = tid & 3;
        const int grow = bid * ROWS_PER_BLOCK + r;
        const float4* xr = (const float4*)(x + (size_t)grow * DIM) + c4 * 4;
        const float4* qr = (const float4*)(eT + pick[r] * DIM) + c4 * 4;
        float4* orow = ((float4*)out) + (size_t)grow * 16 + c4 * 4;
        float lsum = 0.0f;
        #pragma unroll
        for (int j = 0; j < 4; ++j) {
            const float4 q = qr[j], xv = xr[j];
            float4 o; float dx;
            dx = q.x - xv.x; o.x = xv.x + dx; lsum = fmaf(dx, dx, lsum);
            dx = q.y - xv.y; o.y = xv.y + dx; lsum = fmaf(dx, dx, lsum);
            dx = q.z - xv.z; o.z = xv.z + dx; lsum = fmaf(dx, dx, lsum);
            dx = q.w - xv.w; o.w = xv.w + dx; lsum = fmaf(dx, dx, lsum);
            orow[j] = o;
        }
        double dl = (double)lsum;
        #pragma unroll
        for (int off = 32; off > 0; off >>= 1) dl += __shfl_down(dl, off);
        if (l == 0) lpart[w] = dl;
    }
    __syncthreads();
    if (tid == 0) {
        double s = lpart[0];
        #pragma unroll
        for (int t = 1; t < 8; ++t) s += lpart[t];
        atomicAdd(loss_acc, s);
    }
}

__global__ void vq_fin(const double* __restrict__ loss_acc, float* __restrict__ out) {
    if (threadIdx.x == 0)
        out[N_ROWS * DIM] = (float)(1.25 * loss_acc[0] * (1.0 / (double)(N_ROWS * DIM)));
}

extern "C" void kernel_launch(void* const* d_in, const int* in_sizes, int n_in,
                              void* d_out, int out_size, void* d_ws, size_t ws_size,
                              hipStream_t stream) {
    const float* x   = (const float*)d_in[0];
    const float* emb = (const float*)d_in[1];
    float* out = (float*)d_out;
    char*  ws  = (char*)d_ws;

    vq_prep<<<2, 256, 0, stream>>>(emb, ws);
    vq_main<<<N_ROWS / ROWS_PER_BLOCK, THREADS, 0, stream>>>(
        x, ws, out, (double*)(ws + LOSS_OFF));
    vq_fin<<<1, 1, 0, stream>>>((const double*)(ws + LOSS_OFF), out);
}

// Round 14
// 45.834 us; speedup vs baseline: 2.5182x; 1.1859x over previous
//
#include <hip/hip_runtime.h>

// VectorQuantizer forward, fused 3-launch structure + cooperative cvt:
//   prep: codebook -> ws (eT f32, en2, en2b, bf16 hi+lo A-frags)  [2 blocks]
//   main: Phase0 cooperative x->bf16 cvt into LDS frag layout (once/block),
//         Phase1 3-term bf16 MFMA scan (B-frags via conflict-free ds_read),
//         Phase2 combine + near-tie flag, Phase3 exact rescan (round-2 chain),
//         Phase4 streaming epilogue + loss
//   fin:  loss scalar
//
// Metric: argmin_k ||f-e_k||^2 == argmin_k (en2[k]-2 f.e_k). Approx dot =
// fh.eh + fh.el + fl.eh (bf16 splits), residual fl.el sigma ~4e-6;
// TAU=1.2e-3 (validated rounds 5/12/13, absmax 0). en2b = en2+6 keeps the
// metric positive -> u32 bit-monotone pack, code idx in low 9 bits ==
// np.argmin first-index tie-break. cvt8 grouping (8-aligned dims) identical
// to round 13 -> same bf16 inputs -> same picks.

#define N_ROWS 65536
#define DIM 64
#define KCODES 512
#define ROWS_PER_BLOCK 128
#define THREADS 512

typedef short s16x8 __attribute__((ext_vector_type(8)));
typedef float f32x4 __attribute__((ext_vector_type(4)));

// ws byte offsets
#define LOSS_OFF   0
#define EN2_OFF    256
#define EN2B_OFF   2304
#define ET_OFF     4352      // f32 codebook rows: 128 KB
#define AFR_OFF    135424    // bf16 hi+lo A-frags: 128 KB

#define TAU 1.2e-3f

__device__ __forceinline__ unsigned short f2bf(float f) {
    unsigned u = __float_as_uint(f);
    return (unsigned short)((u + 0x7fffu + ((u >> 16) & 1u)) >> 16);
}
__device__ __forceinline__ float bf2f(unsigned short h) {
    return __uint_as_float(((unsigned)h) << 16);
}
__device__ __forceinline__ void cvt8(const float* __restrict__ p,
                                     s16x8& hi, s16x8& lo) {
    const float4 v0 = *(const float4*)p;
    const float4 v1 = *(const float4*)(p + 4);
    const float vv[8] = {v0.x, v0.y, v0.z, v0.w, v1.x, v1.y, v1.z, v1.w};
    #pragma unroll
    for (int j = 0; j < 8; ++j) {
        const unsigned short h = f2bf(vv[j]);
        hi[j] = (short)h;
        lo[j] = (short)f2bf(vv[j] - bf2f(h));
    }
}

// ---------------- prep: codebook only (2 blocks x 256 threads)
__global__ void vq_prep(const float* __restrict__ emb, char* __restrict__ ws) {
    const int k = blockIdx.x * 256 + threadIdx.x;   // code 0..511
    if (k == 0) *(double*)(ws + LOSS_OFF) = 0.0;
    float* en2  = (float*)(ws + EN2_OFF);
    float* en2b = (float*)(ws + EN2B_OFF);
    float* eT   = (float*)(ws + ET_OFF);
    uint4* Afr  = (uint4*)(ws + AFR_OFF);
    const int ctg = k >> 4, c = k & 15;
    float s = 0.0f;
    #pragma unroll
    for (int ks = 0; ks < 2; ++ks) {
        #pragma unroll
        for (int g = 0; g < 4; ++g) {
            unsigned short hb[8], lb[8];
            #pragma unroll
            for (int j = 0; j < 8; ++j) {
                const int d = ks * 32 + g * 8 + j;
                const float v = emb[d * KCODES + k];   // coalesced across k
                eT[k * DIM + d] = v;
                s = fmaf(v, v, s);                     // same chain as round-2
                const unsigned short h = f2bf(v);
                hb[j] = h;
                lb[j] = f2bf(v - bf2f(h));
            }
            uint4 H, L;
            H.x = hb[0] | ((unsigned)hb[1] << 16); H.y = hb[2] | ((unsigned)hb[3] << 16);
            H.z = hb[4] | ((unsigned)hb[5] << 16); H.w = hb[6] | ((unsigned)hb[7] << 16);
            L.x = lb[0] | ((unsigned)lb[1] << 16); L.y = lb[2] | ((unsigned)lb[3] << 16);
            L.z = lb[4] | ((unsigned)lb[5] << 16); L.w = lb[6] | ((unsigned)lb[7] << 16);
            const int lane = g * 16 + c;
            Afr[((ctg * 2 + ks) * 2 + 0) * 64 + lane] = H;   // hi
            Afr[((ctg * 2 + ks) * 2 + 1) * 64 + lane] = L;   // lo
        }
    }
    en2[k] = s;
    en2b[k] = s + 6.0f;
}

// ---------------- main: coop cvt + scan + rescan + epilogue
__global__ __launch_bounds__(THREADS, 2)
void vq_main(const float* __restrict__ x, const char* __restrict__ ws,
             float* __restrict__ out, double* __restrict__ loss_acc) {
    __shared__ s16x8 Bfr[8][2][2][64];                // 32 KB B-fragments
    __shared__ unsigned long long sm_all[8][8][16];   // 8 KB
    __shared__ unsigned pick[ROWS_PER_BLOCK];
    __shared__ unsigned char llist[ROWS_PER_BLOCK];
    __shared__ float fbuf[DIM];
    __shared__ unsigned long long wmin[8];
    __shared__ double lpart[8];
    __shared__ int lcnt;

    const int tid = threadIdx.x;
    const int bid = blockIdx.x;
    const int w = __builtin_amdgcn_readfirstlane(tid >> 6);  // wave = 64-code group
    const int l = tid & 63;
    if (tid == 0) lcnt = 0;

    // Phase 0: cooperative x->frag conversion, once per block.
    // Thread t: row = t>>2 (coalesced 64B/thread), dims seg*16..+16.
    {
        const int r_abs = tid >> 2;          // 0..127
        const int seg   = tid & 3;
        const float* p = x + (size_t)(bid * ROWS_PER_BLOCK + r_abs) * DIM + seg * 16;
        s16x8 h0, l0, h1, l1;
        cvt8(p, h0, l0);                     // dims seg*16   .. +8
        cvt8(p + 8, h1, l1);                 // dims seg*16+8 .. +16
        const int rt = r_abs >> 4, c = r_abs & 15;
        const int jg0 = seg * 2, jg1 = seg * 2 + 1;   // 8-dim group 0..7
        Bfr[rt][jg0 >> 2][0][(jg0 & 3) * 16 + c] = h0;
        Bfr[rt][jg0 >> 2][1][(jg0 & 3) * 16 + c] = l0;
        Bfr[rt][jg1 >> 2][0][(jg1 & 3) * 16 + c] = h1;
        Bfr[rt][jg1 >> 2][1][(jg1 & 3) * 16 + c] = l1;
    }

    // A-fragments: this wave's 64 codes (4 ctiles x 2 ksteps), bf16 hi+lo.
    const s16x8* Afr = (const s16x8*)(ws + AFR_OFF);
    s16x8 Aeh[4][2], Ael[4][2];
    #pragma unroll
    for (int ct = 0; ct < 4; ++ct) {
        #pragma unroll
        for (int ks = 0; ks < 2; ++ks) {
            const int ctg = w * 4 + ct;
            Aeh[ct][ks] = Afr[((ctg * 2 + ks) * 2 + 0) * 64 + l];
            Ael[ct][ks] = Afr[((ctg * 2 + ks) * 2 + 1) * 64 + l];
        }
    }
    const float* en2b = (const float*)(ws + EN2B_OFF);
    f32x4 enf[4];
    #pragma unroll
    for (int ct = 0; ct < 4; ++ct) {
        const float4 t = *(const float4*)(en2b + w * 64 + ct * 16 + (l >> 4) * 4);
        enf[ct][0] = t.x; enf[ct][1] = t.y; enf[ct][2] = t.z; enf[ct][3] = t.w;
    }
    const int codebase = w * 64 + (l >> 4) * 4;

    __syncthreads();   // B-frags ready

    // Phase 1: scan 8 row-tiles; B-frags from LDS (conflict-free ds_read_b128).
    #pragma unroll 2
    for (int bt = 0; bt < 8; ++bt) {
        const s16x8 bh0 = Bfr[bt][0][0][l];
        const s16x8 bl0 = Bfr[bt][0][1][l];
        const s16x8 bh1 = Bfr[bt][1][0][l];
        const s16x8 bl1 = Bfr[bt][1][1][l];

        unsigned m1 = 0xFFFFFFFFu, m2 = 0xFFFFFFFFu;
        #pragma unroll
        for (int ct = 0; ct < 4; ++ct) {
            f32x4 a = {0.f, 0.f, 0.f, 0.f};
            a = __builtin_amdgcn_mfma_f32_16x16x32_bf16(Aeh[ct][0], bh0, a, 0, 0, 0);
            a = __builtin_amdgcn_mfma_f32_16x16x32_bf16(Aeh[ct][1], bh1, a, 0, 0, 0);
            a = __builtin_amdgcn_mfma_f32_16x16x32_bf16(Ael[ct][0], bh0, a, 0, 0, 0);
            a = __builtin_amdgcn_mfma_f32_16x16x32_bf16(Ael[ct][1], bh1, a, 0, 0, 0);
            a = __builtin_amdgcn_mfma_f32_16x16x32_bf16(Aeh[ct][0], bl0, a, 0, 0, 0);
            a = __builtin_amdgcn_mfma_f32_16x16x32_bf16(Aeh[ct][1], bl1, a, 0, 0, 0);
            #pragma unroll
            for (int rg = 0; rg < 4; ++rg) {
                const float m = fmaf(-2.0f, a[rg], enf[ct][rg]);
                const unsigned u = (__float_as_uint(m) & 0xFFFFFE00u)
                                 | (unsigned)(codebase + ct * 16 + rg);
                const unsigned hi = m1 > u ? m1 : u;
                m1 = m1 < u ? m1 : u;
                m2 = m2 < hi ? m2 : hi;
            }
        }
        #pragma unroll
        for (int mask = 16; mask <= 32; mask <<= 1) {
            const unsigned o1 = __shfl_xor(m1, mask);
            const unsigned o2 = __shfl_xor(m2, mask);
            const unsigned hi  = m1 > o1 ? m1 : o1;
            const unsigned lo2 = m2 < o2 ? m2 : o2;
            m1 = m1 < o1 ? m1 : o1;
            m2 = hi < lo2 ? hi : lo2;
        }
        if (l < 16) sm_all[bt][w][l] = ((unsigned long long)m1 << 32) | m2;
    }
    __syncthreads();

    // Phase 2: combine 8 waves per row; flag near-ties (block-local list).
    if (tid < ROWS_PER_BLOCK) {
        const int bt = tid >> 4, c = tid & 15;
        unsigned long long p = sm_all[bt][0][c];
        unsigned m1 = (unsigned)(p >> 32), m2 = (unsigned)p;
        #pragma unroll
        for (int w2 = 1; w2 < 8; ++w2) {
            p = sm_all[bt][w2][c];
            const unsigned a1 = (unsigned)(p >> 32), a2 = (unsigned)p;
            const unsigned hi  = m1 > a1 ? m1 : a1;
            const unsigned lo2 = m2 < a2 ? m2 : a2;
            m1 = m1 < a1 ? m1 : a1;
            m2 = hi < lo2 ? hi : lo2;
        }
        pick[tid] = m1 & 0x1FFu;
        const float f1 = __uint_as_float(m1 & 0xFFFFFE00u);
        const float f2 = __uint_as_float(m2 & 0xFFFFFE00u);
        if (f2 - f1 < TAU) {
            const int i = atomicAdd(&lcnt, 1);
            llist[i] = (unsigned char)tid;
        }
    }
    __syncthreads();

    // Phase 3: exact f32 rescan of flagged rows, block-parallel (1 code/thread,
    // round-2-identical per-code chain; u64 min == np.argmin tie-break).
    {
        const float* eT  = (const float*)(ws + ET_OFF);
        const float* en2 = (const float*)(ws + EN2_OFF);
        const int nfb = lcnt;
        for (int i = 0; i < nfb; ++i) {
            const int r = llist[i];
            const int grow = bid * ROWS_PER_BLOCK + r;
            if (tid < 64) fbuf[tid] = x[(size_t)grow * DIM + tid];
            __syncthreads();

            const float4* fr = (const float4*)fbuf;
            float4 a4 = make_float4(0.f, 0.f, 0.f, 0.f);
            #pragma unroll
            for (int j = 0; j < 16; ++j) {
                const float4 f = fr[j];
                a4.x = fmaf(f.x, f.x, a4.x);
                a4.y = fmaf(f.y, f.y, a4.y);
                a4.z = fmaf(f.z, f.z, a4.z);
                a4.w = fmaf(f.w, f.w, a4.w);
            }
            const float r2 = (a4.x + a4.y) + (a4.z + a4.w);

            const int k = tid;   // one code per thread
            const float4* ek = (const float4*)(eT + k * DIM);
            float4 acc4 = make_float4(0.f, 0.f, 0.f, 0.f);
            #pragma unroll
            for (int j = 0; j < 16; ++j) {
                const float4 e = ek[j];
                const float4 f = fr[j];
                acc4.x = fmaf(f.x, e.x, acc4.x);
                acc4.y = fmaf(f.y, e.y, acc4.y);
                acc4.z = fmaf(f.z, e.z, acc4.z);
                acc4.w = fmaf(f.w, e.w, acc4.w);
            }
            const float dot = (acc4.x + acc4.y) + (acc4.z + acc4.w);
            const float s = (r2 + en2[k]) - 2.0f * dot;
            unsigned long long best =
                ((unsigned long long)__float_as_uint(s) << 32) | (unsigned)k;
            #pragma unroll
            for (int mask = 1; mask <= 32; mask <<= 1) {
                const unsigned long long o = __shfl_xor(best, mask);
                if (o < best) best = o;
            }
            if (l == 0) wmin[w] = best;
            __syncthreads();
            if (tid == 0) {
                unsigned long long b = wmin[0];
                #pragma unroll
                for (int t = 1; t < 8; ++t) if (wmin[t] < b) b = wmin[t];
                pick[r] = (unsigned)(b & 0x1FFu);
            }
            __syncthreads();
        }
    }
    __syncthreads();

    // Phase 4: out = x + (q - x) and loss (4 threads per row, x re-read L2-hot)
    {
        const float* eT = (const float*)(ws + ET_OFF);
        const int r = tid >> 2, c4 = tid & 3;
        const int grow = bid * ROWS_PER_BLOCK + r;
        const float4* xr = (const float4*)(x + (size_t)grow * DIM) + c4 * 4;
        const float4* qr = (const float4*)(eT + pick[r] * DIM) + c4 * 4;
        float4* orow = ((float4*)out) + (size_t)grow * 16 + c4 * 4;
        float lsum = 0.0f;
        #pragma unroll
        for (int j = 0; j < 4; ++j) {
            const float4 q = qr[j], xv = xr[j];
            float4 o; float dx;
            dx = q.x - xv.x; o.x = xv.x + dx; lsum = fmaf(dx, dx, lsum);
            dx = q.y - xv.y; o.y = xv.y + dx; lsum = fmaf(dx, dx, lsum);
            dx = q.z - xv.z; o.z = xv.z + dx; lsum = fmaf(dx, dx, lsum);
            dx = q.w - xv.w; o.w = xv.w + dx; lsum = fmaf(dx, dx, lsum);
            orow[j] = o;
        }
        double dl = (double)lsum;
        #pragma unroll
        for (int off = 32; off > 0; off >>= 1) dl += __shfl_down(dl, off);
        if (l == 0) lpart[w] = dl;
    }
    __syncthreads();
    if (tid == 0) {
        double s = lpart[0];
        #pragma unroll
        for (int t = 1; t < 8; ++t) s += lpart[t];
        atomicAdd(loss_acc, s);
    }
}

__global__ void vq_fin(const double* __restrict__ loss_acc, float* __restrict__ out) {
    if (threadIdx.x == 0)
        out[N_ROWS * DIM] = (float)(1.25 * loss_acc[0] * (1.0 / (double)(N_ROWS * DIM)));
}

extern "C" void kernel_launch(void* const* d_in, const int* in_sizes, int n_in,
                              void* d_out, int out_size, void* d_ws, size_t ws_size,
                              hipStream_t stream) {
    const float* x   = (const float*)d_in[0];
    const float* emb = (const float*)d_in[1];
    float* out = (float*)d_out;
    char*  ws  = (char*)d_ws;

    vq_prep<<<2, 256, 0, stream>>>(emb, ws);
    vq_main<<<N_ROWS / ROWS_PER_BLOCK, THREADS, 0, stream>>>(
        x, ws, out, (double*)(ws + LOSS_OFF));
    vq_fin<<<1, 1, 0, stream>>>((const double*)(ws + LOSS_OFF), out);
}